// Round 2
// baseline (12454.104 us; speedup 1.0000x reference)
//
#include <hip/hip_runtime.h>
#include <stdint.h>

#define B_ 64
#define T_ 256
#define XD_ 128
#define X2S_ 256
#define HD_ 512
#define ZD_ 64
#define G3_ 1536

typedef unsigned short bf16u;
typedef __attribute__((ext_vector_type(8))) short short8;
typedef __attribute__((ext_vector_type(4))) float f32x4;

__device__ inline f32x4 MFMA(short8 a, short8 b, f32x4 c){
  return __builtin_amdgcn_mfma_f32_16x16x32_bf16(a, b, c, 0, 0, 0);
}
__device__ inline bf16u f2bf(float f){
  unsigned int u = __float_as_uint(f);
  u = u + 0x7FFFu + ((u >> 16) & 1u);
  return (bf16u)(u >> 16);
}
__device__ inline float bf2f(bf16u h){ return __uint_as_float(((unsigned int)h) << 16); }
__device__ inline float sigmoidf_(float x){ return 1.0f / (1.0f + expf(-x)); }
__device__ inline float softplusf_(float x){ return fmaxf(x, 0.0f) + log1pf(expf(-fabsf(x))); }

// ---- fragment helpers -------------------------------------------------------
// Packed weight layout: for W[K,N] bf16: dst[((nt*(K/32)+kc)*64 + lane)*8 + j]
//   = W[kc*32 + (lane>>4)*8 + j][nt*16 + (lane&15)]
__device__ inline short8 wfrag(const bf16u* Wp, int K, int nt, int kc, int lane){
  return *(const short8*)(Wp + (((size_t)nt * (K >> 5) + kc) * 64 + lane) * 8);
}
// A fragment straight from global row-major [M, rowstride] bf16
__device__ inline short8 afrag_g(const bf16u* A, int rowstride, int m0, int kc, int lane){
  return *(const short8*)(A + (size_t)(m0 + (lane & 15)) * rowstride + kc * 32 + ((lane >> 4) << 3));
}
// A fragment from LDS [16][KB bytes], XOR-swizzled rows
__device__ inline short8 afrag_l(const char* buf, int KB, int kc, int lane){
  int row = lane & 15;
  int kb  = kc * 64 + ((lane >> 4) << 4);
  return *(const short8*)(buf + row * KB + (kb ^ ((row & 7) << 4)));
}
__device__ inline void lds_store_bf(char* buf, int KB, int row, int col, bf16u v){
  int byte = col * 2;
  *(bf16u*)(buf + row * KB + (byte ^ ((row & 7) << 4))) = v;
}

// ---- weight packing ---------------------------------------------------------
__global__ void pack_w(const float* __restrict__ src, bf16u* __restrict__ dst, int K, int N){
  int lane = threadIdx.x;            // 64
  int idx  = blockIdx.x;             // nt*(K/32)+kc
  int KC = K >> 5;
  int nt = idx / KC, kc = idx - nt * KC;
  int col = nt * 16 + (lane & 15);
  int k0  = kc * 32 + ((lane >> 4) << 3);
  short8 v;
#pragma unroll
  for (int j = 0; j < 8; ++j) v[j] = (short)f2bf(src[(size_t)(k0 + j) * N + col]);
  *(short8*)(dst + ((size_t)idx * 64 + lane) * 8) = v;
}

__global__ void cvt_bf(const float* __restrict__ src, bf16u* __restrict__ dst, int n){
  int i = blockIdx.x * 256 + threadIdx.x;
  if (i < n) dst[i] = f2bf(src[i]);
}

// ---- generic big GEMM: C[M,N] = act(A@W + bias), A row-major bf16 ----------
// STORE 0: bf16 out at row r.  STORE 1: bf16 out permuted r=(b*256+t) -> (t*64+b)
template<int ACT, int STORE>
__global__ __launch_bounds__(256)
void gemm_big(const bf16u* __restrict__ A1, int K1,
              const bf16u* __restrict__ A2, int K2,
              const bf16u* __restrict__ Wp,
              const float* __restrict__ bias,
              bf16u* __restrict__ outb, int N){
  int lane = threadIdx.x & 63, wave = threadIdx.x >> 6;
  int m0 = blockIdx.x * 64 + wave * 16;
  int K = K1 + K2;
  int nt0 = blockIdx.y * 4;
  for (int ntl = 0; ntl < 4; ++ntl){
    int nt = nt0 + ntl;
    f32x4 acc = {0.f, 0.f, 0.f, 0.f};
    int KC1 = K1 >> 5;
    for (int kc = 0; kc < KC1; ++kc)
      acc = MFMA(afrag_g(A1, K1, m0, kc, lane), wfrag(Wp, K, nt, kc, lane), acc);
    if (A2){
      int KC2 = K2 >> 5;
      for (int kc = 0; kc < KC2; ++kc)
        acc = MFMA(afrag_g(A2, K2, m0, kc, lane), wfrag(Wp, K, nt, KC1 + kc, lane), acc);
    }
#pragma unroll
    for (int r = 0; r < 4; ++r){
      int row = m0 + ((lane >> 4) << 2) + r;
      int col = nt * 16 + (lane & 15);
      float v = acc[r] + (bias ? bias[col] : 0.f);
      if (ACT == 1) v = fmaxf(v, 0.f);
      if (STORE == 0){
        outb[(size_t)row * N + col] = f2bf(v);
      } else {
        int b = row >> 8, t = row & 255;
        outb[(size_t)(t * 64 + b) * N + col] = f2bf(v);
      }
    }
  }
}

// ---- theta heads: mu (linear) + sig (softplus), fp32 out, r=(t*64+b)->(b,t)
__global__ __launch_bounds__(256)
void gemm_heads(const bf16u* __restrict__ A,
                const bf16u* __restrict__ Wmu, const bf16u* __restrict__ Wsig,
                const float* __restrict__ bmu, const float* __restrict__ bsig,
                float* __restrict__ out_mu, float* __restrict__ out_sig){
  int lane = threadIdx.x & 63, wave = threadIdx.x >> 6;
  int m0 = blockIdx.x * 64 + wave * 16;
  int nt0 = blockIdx.y * 4;
  for (int ntl = 0; ntl < 4; ++ntl){
    int nt = nt0 + ntl;
    f32x4 am = {0.f,0.f,0.f,0.f}, as = {0.f,0.f,0.f,0.f};
    for (int kc = 0; kc < 8; ++kc){
      short8 a = afrag_g(A, 256, m0, kc, lane);
      am = MFMA(a, wfrag(Wmu, 256, nt, kc, lane), am);
      as = MFMA(a, wfrag(Wsig, 256, nt, kc, lane), as);
    }
#pragma unroll
    for (int r = 0; r < 4; ++r){
      int row = m0 + ((lane >> 4) << 2) + r;
      int col = nt * 16 + (lane & 15);
      int b = row & 63, t = row >> 6;
      size_t o = (size_t)(b * 256 + t) * 128 + col;
      out_mu[o]  = am[r] + bmu[col];
      out_sig[o] = softplusf_(as[r] + bsig[col]);
    }
  }
}

// ---- scan context -----------------------------------------------------------
struct Ctx {
  const bf16u *Wp1t, *Wp1b, *Wp2, *Wpmu, *Wpsig, *Wz1, *Wz2, *k1t, *k1b, *rk1, *k2, *rk2;
  const float *bp1, *bp2, *bpmu, *bpsig, *bz1, *bz2, *b1, *b2, *eps;
  const bf16u *X2t;            // [t*64+b][256]
  bf16u *zp_all, *S_all, *h1b, *h4b;
  float *h1f, *h4f, *mh1, *mh4, *out_z;
};

// K_A: blocks 0-3: phi chain (16 rows each). blocks 4-19: mh1/mh4 N-split.
__global__ __launch_bounds__(256)
void k_step_A(Ctx c, int t){
  __shared__ __align__(16) char A0[16 * 1024];
  __shared__ __align__(16) char A1s[16 * 512];
  __shared__ __align__(16) char A2s[16 * 512];
  __shared__ __align__(16) char A3s[16 * 128];
  int lane = threadIdx.x & 63, wave = threadIdx.x >> 6;
  if (blockIdx.x < 4){
    int b0 = blockIdx.x * 16;
    const bf16u* X2row = c.X2t + (size_t)t * 64 * 256;
    // stage h4 (bf16) into swizzled LDS
    for (int i = threadIdx.x; i < 1024; i += 256){
      int r = i >> 6, ch = i & 63;
      *(short8*)(A0 + r * 1024 + ((ch * 16) ^ ((r & 7) << 4))) =
          *(const short8*)(c.h4b + (size_t)(b0 + r) * 512 + ch * 8);
    }
    __syncthreads();
    // phi1 = relu(x2@Wp1[:256] + h4@Wp1[256:] + bp1)  -> A1s [16][256]
    for (int nt = wave; nt < 16; nt += 4){
      f32x4 acc = {0.f,0.f,0.f,0.f};
#pragma unroll
      for (int kc = 0; kc < 8; ++kc)
        acc = MFMA(afrag_g(X2row, 256, b0, kc, lane), wfrag(c.Wp1t, 256, nt, kc, lane), acc);
#pragma unroll
      for (int kc = 0; kc < 16; ++kc)
        acc = MFMA(afrag_l(A0, 1024, kc, lane), wfrag(c.Wp1b, 512, nt, kc, lane), acc);
#pragma unroll
      for (int r = 0; r < 4; ++r){
        int row = ((lane >> 4) << 2) + r, col = nt * 16 + (lane & 15);
        lds_store_bf(A1s, 512, row, col, f2bf(fmaxf(acc[r] + c.bp1[col], 0.f)));
      }
    }
    __syncthreads();
    // phi2 = relu(phi1@Wp2 + bp2) -> A2s
    for (int nt = wave; nt < 16; nt += 4){
      f32x4 acc = {0.f,0.f,0.f,0.f};
#pragma unroll
      for (int kc = 0; kc < 8; ++kc)
        acc = MFMA(afrag_l(A1s, 512, kc, lane), wfrag(c.Wp2, 256, nt, kc, lane), acc);
#pragma unroll
      for (int r = 0; r < 4; ++r){
        int row = ((lane >> 4) << 2) + r, col = nt * 16 + (lane & 15);
        lds_store_bf(A2s, 512, row, col, f2bf(fmaxf(acc[r] + c.bp2[col], 0.f)));
      }
    }
    __syncthreads();
    // heads: pmu, psig -> z = pmu + softplus(psig_pre)*eps ; write z out + A3s
    {
      int nt = wave;  // N=64 -> 4 ntiles
      f32x4 am = {0.f,0.f,0.f,0.f}, as = {0.f,0.f,0.f,0.f};
#pragma unroll
      for (int kc = 0; kc < 8; ++kc){
        short8 a = afrag_l(A2s, 512, kc, lane);
        am = MFMA(a, wfrag(c.Wpmu, 256, nt, kc, lane), am);
        as = MFMA(a, wfrag(c.Wpsig, 256, nt, kc, lane), as);
      }
#pragma unroll
      for (int r = 0; r < 4; ++r){
        int row = ((lane >> 4) << 2) + r, col = nt * 16 + (lane & 15);
        float mu = am[r] + c.bpmu[col];
        float sg = softplusf_(as[r] + c.bpsig[col]);
        int b = b0 + row;
        float e = c.eps[((size_t)b * 256 + t) * 64 + col];
        float z = mu + sg * e;
        c.out_z[((size_t)b * 256 + t) * 64 + col] = z;
        lds_store_bf(A3s, 128, row, col, f2bf(z));
      }
    }
    __syncthreads();
    // zp1 = relu(z@Wz1 + bz1) -> A1s (reuse)
    for (int nt = wave; nt < 16; nt += 4){
      f32x4 acc = {0.f,0.f,0.f,0.f};
#pragma unroll
      for (int kc = 0; kc < 2; ++kc)
        acc = MFMA(afrag_l(A3s, 128, kc, lane), wfrag(c.Wz1, 64, nt, kc, lane), acc);
#pragma unroll
      for (int r = 0; r < 4; ++r){
        int row = ((lane >> 4) << 2) + r, col = nt * 16 + (lane & 15);
        lds_store_bf(A1s, 512, row, col, f2bf(fmaxf(acc[r] + c.bz1[col], 0.f)));
      }
    }
    __syncthreads();
    // zp2 = relu(zp1@Wz2 + bz2) -> zp_all[t]
    for (int nt = wave; nt < 16; nt += 4){
      f32x4 acc = {0.f,0.f,0.f,0.f};
#pragma unroll
      for (int kc = 0; kc < 8; ++kc)
        acc = MFMA(afrag_l(A1s, 512, kc, lane), wfrag(c.Wz2, 256, nt, kc, lane), acc);
#pragma unroll
      for (int r = 0; r < 4; ++r){
        int row = ((lane >> 4) << 2) + r, col = nt * 16 + (lane & 15);
        c.zp_all[(size_t)(t * 64 + b0 + row) * 256 + col] = f2bf(fmaxf(acc[r] + c.bz2[col], 0.f));
      }
    }
  } else {
    // mh1 = h1@rk1 + b1[1],  mh4 = h4@rk2 + b2[1]   (fp32 buffers)
    int wg = blockIdx.x - 4;   // 0..15, hidden slice j0..j0+32
    int j0 = wg * 32;
    int m0 = wave * 16;
    const f32x4 Z4 = {0.f,0.f,0.f,0.f};
    f32x4 acc[6];
#pragma unroll
    for (int i = 0; i < 6; ++i) acc[i] = Z4;
    for (int kc = 0; kc < 16; ++kc){
      short8 a = afrag_g(c.h1b, 512, m0, kc, lane);
#pragma unroll
      for (int g = 0; g < 3; ++g)
#pragma unroll
        for (int i = 0; i < 2; ++i){
          int nt = g * 32 + wg * 2 + i;
          acc[g * 2 + i] = MFMA(a, wfrag(c.rk1, 512, nt, kc, lane), acc[g * 2 + i]);
        }
    }
#pragma unroll
    for (int g = 0; g < 3; ++g)
#pragma unroll
      for (int i = 0; i < 2; ++i)
#pragma unroll
        for (int r = 0; r < 4; ++r){
          int row = m0 + ((lane >> 4) << 2) + r;
          int col = g * 512 + j0 + i * 16 + (lane & 15);
          c.mh1[(size_t)row * 1536 + col] = acc[g * 2 + i][r] + c.b1[1536 + col];
        }
#pragma unroll
    for (int i = 0; i < 6; ++i) acc[i] = Z4;
    for (int kc = 0; kc < 16; ++kc){
      short8 a = afrag_g(c.h4b, 512, m0, kc, lane);
#pragma unroll
      for (int g = 0; g < 3; ++g)
#pragma unroll
        for (int i = 0; i < 2; ++i){
          int nt = g * 32 + wg * 2 + i;
          acc[g * 2 + i] = MFMA(a, wfrag(c.rk2, 512, nt, kc, lane), acc[g * 2 + i]);
        }
    }
#pragma unroll
    for (int g = 0; g < 3; ++g)
#pragma unroll
      for (int i = 0; i < 2; ++i)
#pragma unroll
        for (int r = 0; r < 4; ++r){
          int row = m0 + ((lane >> 4) << 2) + r;
          int col = g * 512 + j0 + i * 16 + (lane & 15);
          c.mh4[(size_t)row * 1536 + col] = acc[g * 2 + i][r] + c.b2[1536 + col];
        }
  }
}

// K_B: mx1 = x2@k1[:256] + zp@k1[256:] + b1[0]; s1 = GRU-combine -> h1f/h1b
__global__ __launch_bounds__(256)
void k_step_B(Ctx c, int t){
  int lane = threadIdx.x & 63, wave = threadIdx.x >> 6;
  int wg = blockIdx.x, j0 = wg * 32, m0 = wave * 16;
  const f32x4 Z4 = {0.f,0.f,0.f,0.f};
  f32x4 acc[6];
#pragma unroll
  for (int i = 0; i < 6; ++i) acc[i] = Z4;
  const bf16u* X2row = c.X2t + (size_t)t * 64 * 256;
  const bf16u* zprow = c.zp_all + (size_t)t * 64 * 256;
  for (int kc = 0; kc < 8; ++kc){
    short8 a = afrag_g(X2row, 256, m0, kc, lane);
#pragma unroll
    for (int g = 0; g < 3; ++g)
#pragma unroll
      for (int i = 0; i < 2; ++i){
        int nt = g * 32 + wg * 2 + i;
        acc[g * 2 + i] = MFMA(a, wfrag(c.k1t, 256, nt, kc, lane), acc[g * 2 + i]);
      }
  }
  for (int kc = 0; kc < 8; ++kc){
    short8 a = afrag_g(zprow, 256, m0, kc, lane);
#pragma unroll
    for (int g = 0; g < 3; ++g)
#pragma unroll
      for (int i = 0; i < 2; ++i){
        int nt = g * 32 + wg * 2 + i;
        acc[g * 2 + i] = MFMA(a, wfrag(c.k1b, 256, nt, kc, lane), acc[g * 2 + i]);
      }
  }
#pragma unroll
  for (int i = 0; i < 2; ++i)
#pragma unroll
    for (int r = 0; r < 4; ++r){
      int row = m0 + ((lane >> 4) << 2) + r;
      int j = j0 + i * 16 + (lane & 15);
      float xz = acc[0 + i][r] + c.b1[j];
      float xr = acc[2 + i][r] + c.b1[512 + j];
      float xh = acc[4 + i][r] + c.b1[1024 + j];
      float hz = c.mh1[(size_t)row * 1536 + j];
      float hr = c.mh1[(size_t)row * 1536 + 512 + j];
      float hh = c.mh1[(size_t)row * 1536 + 1024 + j];
      float ho = c.h1f[(size_t)row * 512 + j];
      float zg = sigmoidf_(xz + hz);
      float rg = sigmoidf_(xr + hr);
      float hc = tanhf(xh + rg * hh);
      float hn = zg * ho + (1.f - zg) * hc;
      c.h1f[(size_t)row * 512 + j] = hn;
      c.h1b[(size_t)row * 512 + j] = f2bf(hn);
    }
}

// K_C: mx2 = s1@k2 + b2[0]; s4 = GRU-combine -> h4f/h4b + S_all[t]
__global__ __launch_bounds__(256)
void k_step_C(Ctx c, int t){
  int lane = threadIdx.x & 63, wave = threadIdx.x >> 6;
  int wg = blockIdx.x, j0 = wg * 32, m0 = wave * 16;
  const f32x4 Z4 = {0.f,0.f,0.f,0.f};
  f32x4 acc[6];
#pragma unroll
  for (int i = 0; i < 6; ++i) acc[i] = Z4;
  for (int kc = 0; kc < 16; ++kc){
    short8 a = afrag_g(c.h1b, 512, m0, kc, lane);
#pragma unroll
    for (int g = 0; g < 3; ++g)
#pragma unroll
      for (int i = 0; i < 2; ++i){
        int nt = g * 32 + wg * 2 + i;
        acc[g * 2 + i] = MFMA(a, wfrag(c.k2, 512, nt, kc, lane), acc[g * 2 + i]);
      }
  }
#pragma unroll
  for (int i = 0; i < 2; ++i)
#pragma unroll
    for (int r = 0; r < 4; ++r){
      int row = m0 + ((lane >> 4) << 2) + r;
      int j = j0 + i * 16 + (lane & 15);
      float xz = acc[0 + i][r] + c.b2[j];
      float xr = acc[2 + i][r] + c.b2[512 + j];
      float xh = acc[4 + i][r] + c.b2[1024 + j];
      float hz = c.mh4[(size_t)row * 1536 + j];
      float hr = c.mh4[(size_t)row * 1536 + 512 + j];
      float hh = c.mh4[(size_t)row * 1536 + 1024 + j];
      float ho = c.h4f[(size_t)row * 512 + j];
      float zg = sigmoidf_(xz + hz);
      float rg = sigmoidf_(xr + hr);
      float hc = tanhf(xh + rg * hh);
      float hn = zg * ho + (1.f - zg) * hc;
      c.h4f[(size_t)row * 512 + j] = hn;
      bf16u hb = f2bf(hn);
      c.h4b[(size_t)row * 512 + j] = hb;
      c.S_all[(size_t)(t * 64 + row) * 512 + j] = hb;
    }
}

// ---- host ------------------------------------------------------------------
extern "C" void kernel_launch(void* const* d_in, const int* in_sizes, int n_in,
                              void* d_out, int out_size, void* d_ws, size_t ws_size,
                              hipStream_t stream){
  const float* inp   = (const float*)d_in[0];
  const float* eps   = (const float*)d_in[1];
  const float* Wx1   = (const float*)d_in[2];  const float* bx1 = (const float*)d_in[3];
  const float* Wx2   = (const float*)d_in[4];  const float* bx2 = (const float*)d_in[5];
  const float* Wz1   = (const float*)d_in[6];  const float* bz1 = (const float*)d_in[7];
  const float* Wz2   = (const float*)d_in[8];  const float* bz2 = (const float*)d_in[9];
  const float* Wp1   = (const float*)d_in[10]; const float* bp1 = (const float*)d_in[11];
  const float* Wp2   = (const float*)d_in[12]; const float* bp2 = (const float*)d_in[13];
  const float* Wpmu  = (const float*)d_in[14]; const float* bpmu = (const float*)d_in[15];
  const float* Wpsig = (const float*)d_in[16]; const float* bpsig = (const float*)d_in[17];
  // d_in[18..25]: prior path (Wr1,br1,Wr2,br2,Wrmu,brmu,Wrsig,brsig) -> DEAD (not in outputs)
  const float* Wt1   = (const float*)d_in[26]; const float* bt1 = (const float*)d_in[27];
  const float* Wt2   = (const float*)d_in[28]; const float* bt2 = (const float*)d_in[29];
  const float* Wtmu  = (const float*)d_in[30]; const float* btmu = (const float*)d_in[31];
  const float* Wtsig = (const float*)d_in[32]; const float* btsig = (const float*)d_in[33];
  const float* k1    = (const float*)d_in[34];
  const float* rk1   = (const float*)d_in[35];
  const float* b1    = (const float*)d_in[36];
  const float* k2    = (const float*)d_in[37];
  const float* rk2   = (const float*)d_in[38];
  const float* b2    = (const float*)d_in[39];

  float* out_mu  = (float*)d_out;
  float* out_sig = out_mu + (size_t)16384 * 128;
  float* out_z   = out_sig + (size_t)16384 * 128;

  char* p = (char*)d_ws;
  auto alloc = [&](size_t bytes)->char*{ char* r = p; p += (bytes + 255) & ~(size_t)255; return r; };

  // packed weights (~7.9 MB)
  bf16u* Wx1p  = (bf16u*)alloc((size_t)128 * 256 * 2);
  bf16u* Wx2p  = (bf16u*)alloc((size_t)256 * 256 * 2);
  bf16u* Wp1t  = (bf16u*)alloc((size_t)256 * 256 * 2);
  bf16u* Wp1b  = (bf16u*)alloc((size_t)512 * 256 * 2);
  bf16u* Wp2p  = (bf16u*)alloc((size_t)256 * 256 * 2);
  bf16u* Wpmup = (bf16u*)alloc((size_t)256 * 64 * 2);
  bf16u* Wpsigp= (bf16u*)alloc((size_t)256 * 64 * 2);
  bf16u* Wz1p  = (bf16u*)alloc((size_t)64 * 256 * 2);
  bf16u* Wz2p  = (bf16u*)alloc((size_t)256 * 256 * 2);
  bf16u* Wt1p  = (bf16u*)alloc((size_t)768 * 256 * 2);
  bf16u* Wt2p  = (bf16u*)alloc((size_t)256 * 256 * 2);
  bf16u* Wtmup = (bf16u*)alloc((size_t)256 * 128 * 2);
  bf16u* Wtsigp= (bf16u*)alloc((size_t)256 * 128 * 2);
  bf16u* k1t   = (bf16u*)alloc((size_t)256 * 1536 * 2);
  bf16u* k1b   = (bf16u*)alloc((size_t)256 * 1536 * 2);
  bf16u* rk1p  = (bf16u*)alloc((size_t)512 * 1536 * 2);
  bf16u* k2p   = (bf16u*)alloc((size_t)512 * 1536 * 2);
  bf16u* rk2p  = (bf16u*)alloc((size_t)512 * 1536 * 2);

  // activations (aliased where lifetime allows)
  bf16u* Xbf    = (bf16u*)alloc((size_t)16384 * 128 * 2);   // dead after X-MLP layer 1
  bf16u* tmp1   = (bf16u*)alloc((size_t)16384 * 256 * 2);   // dead after X-MLP layer 2 -> reused as th1
  bf16u* X2t    = (bf16u*)alloc((size_t)16384 * 256 * 2);   // [t*64+b][256], dead after scan -> reused as th2
  bf16u* zp_all = (bf16u*)alloc((size_t)16384 * 256 * 2);
  bf16u* S_all  = (bf16u*)alloc((size_t)16384 * 512 * 2);
  float* h1f = (float*)alloc((size_t)64 * 512 * 4);
  float* h4f = (float*)alloc((size_t)64 * 512 * 4);
  bf16u* h1b = (bf16u*)alloc((size_t)64 * 512 * 2);
  bf16u* h4b = (bf16u*)alloc((size_t)64 * 512 * 2);
  float* mh1 = (float*)alloc((size_t)64 * 1536 * 4);
  float* mh4 = (float*)alloc((size_t)64 * 1536 * 4);
  bf16u* th1 = tmp1;   // alias: tmp1 dead once X2t is built
  bf16u* th2 = X2t;    // alias: X2t dead once scan is done

  auto PK = [&](const float* src, bf16u* dst, int K, int N){
    pack_w<<<dim3((N / 16) * (K / 32)), dim3(64), 0, stream>>>(src, dst, K, N);
  };
  PK(Wx1, Wx1p, 128, 256);
  PK(Wx2, Wx2p, 256, 256);
  PK(Wp1, Wp1t, 256, 256);                     // rows 0..255 (x2 part)
  PK(Wp1 + (size_t)256 * 256, Wp1b, 512, 256); // rows 256..767 (h4 part)
  PK(Wp2, Wp2p, 256, 256);
  PK(Wpmu, Wpmup, 256, 64);
  PK(Wpsig, Wpsigp, 256, 64);
  PK(Wz1, Wz1p, 64, 256);
  PK(Wz2, Wz2p, 256, 256);
  PK(Wt1, Wt1p, 768, 256);
  PK(Wt2, Wt2p, 256, 256);
  PK(Wtmu, Wtmup, 256, 128);
  PK(Wtsig, Wtsigp, 256, 128);
  PK(k1, k1t, 256, 1536);                      // rows 0..255 (x2 part)
  PK(k1 + (size_t)256 * 1536, k1b, 256, 1536); // rows 256..511 (zp part)
  PK(rk1, rk1p, 512, 1536);
  PK(k2, k2p, 512, 1536);
  PK(rk2, rk2p, 512, 1536);

  cvt_bf<<<dim3((16384 * 128 + 255) / 256), dim3(256), 0, stream>>>(inp, Xbf, 16384 * 128);
  hipMemsetAsync(h1f, 0, (size_t)64 * 512 * 4, stream);
  hipMemsetAsync(h4f, 0, (size_t)64 * 512 * 4, stream);
  hipMemsetAsync(h1b, 0, (size_t)64 * 512 * 2, stream);
  hipMemsetAsync(h4b, 0, (size_t)64 * 512 * 2, stream);

  // X transform; second layer stores time-major [t*64+b][256]
  gemm_big<1, 0><<<dim3(256, 4), dim3(256), 0, stream>>>(Xbf, 128, nullptr, 0, Wx1p, bx1, tmp1, 256);
  gemm_big<1, 1><<<dim3(256, 4), dim3(256), 0, stream>>>(tmp1, 256, nullptr, 0, Wx2p, bx2, X2t, 256);

  Ctx c;
  c.Wp1t = Wp1t; c.Wp1b = Wp1b; c.Wp2 = Wp2p; c.Wpmu = Wpmup; c.Wpsig = Wpsigp;
  c.Wz1 = Wz1p; c.Wz2 = Wz2p; c.k1t = k1t; c.k1b = k1b; c.rk1 = rk1p; c.k2 = k2p; c.rk2 = rk2p;
  c.bp1 = bp1; c.bp2 = bp2; c.bpmu = bpmu; c.bpsig = bpsig; c.bz1 = bz1; c.bz2 = bz2;
  c.b1 = b1; c.b2 = b2; c.eps = eps;
  c.X2t = X2t; c.zp_all = zp_all; c.S_all = S_all;
  c.h1b = h1b; c.h4b = h4b; c.h1f = h1f; c.h4f = h4f; c.mh1 = mh1; c.mh4 = mh4;
  c.out_z = out_z;

  for (int t = 0; t < 256; ++t){
    k_step_A<<<dim3(20), dim3(256), 0, stream>>>(c, t);
    k_step_B<<<dim3(16), dim3(256), 0, stream>>>(c, t);
    k_step_C<<<dim3(16), dim3(256), 0, stream>>>(c, t);
  }

  // theta decoder (th1 aliases tmp1, th2 aliases X2t — both dead by now)
  gemm_big<1, 0><<<dim3(256, 4), dim3(256), 0, stream>>>(zp_all, 256, S_all, 512, Wt1p, bt1, th1, 256);
  gemm_big<1, 0><<<dim3(256, 4), dim3(256), 0, stream>>>(th1, 256, nullptr, 0, Wt2p, bt2, th2, 256);
  gemm_heads<<<dim3(256, 2), dim3(256), 0, stream>>>(th2, Wtmup, Wtsigp, btmu, btsig, out_mu, out_sig);
}

// Round 4
// 10798.836 us; speedup vs baseline: 1.1533x; 1.1533x over previous
//
#include <hip/hip_runtime.h>
#include <hip/hip_cooperative_groups.h>
#include <stdint.h>

namespace cg = cooperative_groups;

typedef unsigned short bf16u;
typedef __attribute__((ext_vector_type(8))) short short8;
typedef __attribute__((ext_vector_type(4))) float f32x4;

__device__ inline f32x4 MFMA(short8 a, short8 b, f32x4 c){
  return __builtin_amdgcn_mfma_f32_16x16x32_bf16(a, b, c, 0, 0, 0);
}
__device__ inline bf16u f2bf(float f){
  unsigned int u = __float_as_uint(f);
  u = u + 0x7FFFu + ((u >> 16) & 1u);
  return (bf16u)(u >> 16);
}
__device__ inline float bf2f(bf16u h){ return __uint_as_float(((unsigned int)h) << 16); }
__device__ inline float sigmoidf_(float x){ return 1.0f / (1.0f + expf(-x)); }
__device__ inline float softplusf_(float x){ return fmaxf(x, 0.0f) + log1pf(expf(-fabsf(x))); }

// ---- fragment helpers -------------------------------------------------------
// Packed weight layout: for W[K,N] bf16: dst[((nt*(K/32)+kc)*64 + lane)*8 + j]
//   = W[kc*32 + (lane>>4)*8 + j][nt*16 + (lane&15)]
__device__ inline short8 wfrag(const bf16u* Wp, int K, int nt, int kc, int lane){
  return *(const short8*)(Wp + (((size_t)nt * (K >> 5) + kc) * 64 + lane) * 8);
}
__device__ inline short8 afrag_g(const bf16u* A, int rowstride, int m0, int kc, int lane){
  return *(const short8*)(A + (size_t)(m0 + (lane & 15)) * rowstride + kc * 32 + ((lane >> 4) << 3));
}
// A fragment from LDS [16][KB bytes], XOR-swizzled rows
__device__ inline short8 afrag_l(const char* buf, int KB, int kc, int lane){
  int row = lane & 15;
  int kb  = kc * 64 + ((lane >> 4) << 4);
  return *(const short8*)(buf + row * KB + (kb ^ ((row & 7) << 4)));
}
__device__ inline void lds_store_bf(char* buf, int KB, int row, int col, bf16u v){
  int byte = col * 2;
  *(bf16u*)(buf + row * KB + (byte ^ ((row & 7) << 4))) = v;
}
// weight fragment from LDS slab: slab holds nt-blocks of 16KB (16 kc x 1KB)
__device__ inline short8 lfrag(const char* slab, int ntl, int kc, int lane){
  return *(const short8*)(slab + (size_t)(ntl * 16 + kc) * 1024 + lane * 16);
}

// ---- weight packing ---------------------------------------------------------
__global__ void pack_w(const float* __restrict__ src, bf16u* __restrict__ dst, int K, int N){
  int lane = threadIdx.x;            // 64
  int idx  = blockIdx.x;             // nt*(K/32)+kc
  int KC = K >> 5;
  int nt = idx / KC, kc = idx - nt * KC;
  int col = nt * 16 + (lane & 15);
  int k0  = kc * 32 + ((lane >> 4) << 3);
  short8 v;
#pragma unroll
  for (int j = 0; j < 8; ++j) v[j] = (short)f2bf(src[(size_t)(k0 + j) * N + col]);
  *(short8*)(dst + ((size_t)idx * 64 + lane) * 8) = v;
}

__global__ void cvt_bf(const float* __restrict__ src, bf16u* __restrict__ dst, int n){
  int i = blockIdx.x * 256 + threadIdx.x;
  if (i < n) dst[i] = f2bf(src[i]);
}

// ---- generic big GEMM: C[M,N] = act(A@W + bias), A row-major bf16 ----------
template<int ACT, int STORE>
__global__ __launch_bounds__(256)
void gemm_big(const bf16u* __restrict__ A1, int K1,
              const bf16u* __restrict__ A2, int K2,
              const bf16u* __restrict__ Wp,
              const float* __restrict__ bias,
              bf16u* __restrict__ outb, int N){
  int lane = threadIdx.x & 63, wave = threadIdx.x >> 6;
  int m0 = blockIdx.x * 64 + wave * 16;
  int K = K1 + K2;
  int nt0 = blockIdx.y * 4;
  for (int ntl = 0; ntl < 4; ++ntl){
    int nt = nt0 + ntl;
    f32x4 acc = {0.f, 0.f, 0.f, 0.f};
    int KC1 = K1 >> 5;
    for (int kc = 0; kc < KC1; ++kc)
      acc = MFMA(afrag_g(A1, K1, m0, kc, lane), wfrag(Wp, K, nt, kc, lane), acc);
    if (A2){
      int KC2 = K2 >> 5;
      for (int kc = 0; kc < KC2; ++kc)
        acc = MFMA(afrag_g(A2, K2, m0, kc, lane), wfrag(Wp, K, nt, KC1 + kc, lane), acc);
    }
#pragma unroll
    for (int r = 0; r < 4; ++r){
      int row = m0 + ((lane >> 4) << 2) + r;
      int col = nt * 16 + (lane & 15);
      float v = acc[r] + (bias ? bias[col] : 0.f);
      if (ACT == 1) v = fmaxf(v, 0.f);
      if (STORE == 0){
        outb[(size_t)row * N + col] = f2bf(v);
      } else {
        int b = row >> 8, t = row & 255;
        outb[(size_t)(t * 64 + b) * N + col] = f2bf(v);
      }
    }
  }
}

// ---- theta heads -----------------------------------------------------------
__global__ __launch_bounds__(256)
void gemm_heads(const bf16u* __restrict__ A,
                const bf16u* __restrict__ Wmu, const bf16u* __restrict__ Wsig,
                const float* __restrict__ bmu, const float* __restrict__ bsig,
                float* __restrict__ out_mu, float* __restrict__ out_sig){
  int lane = threadIdx.x & 63, wave = threadIdx.x >> 6;
  int m0 = blockIdx.x * 64 + wave * 16;
  int nt0 = blockIdx.y * 4;
  for (int ntl = 0; ntl < 4; ++ntl){
    int nt = nt0 + ntl;
    f32x4 am = {0.f,0.f,0.f,0.f}, as = {0.f,0.f,0.f,0.f};
    for (int kc = 0; kc < 8; ++kc){
      short8 a = afrag_g(A, 256, m0, kc, lane);
      am = MFMA(a, wfrag(Wmu, 256, nt, kc, lane), am);
      as = MFMA(a, wfrag(Wsig, 256, nt, kc, lane), as);
    }
#pragma unroll
    for (int r = 0; r < 4; ++r){
      int row = m0 + ((lane >> 4) << 2) + r;
      int col = nt * 16 + (lane & 15);
      int b = row & 63, t = row >> 6;
      size_t o = (size_t)(b * 256 + t) * 128 + col;
      out_mu[o]  = am[r] + bmu[col];
      out_sig[o] = softplusf_(as[r] + bsig[col]);
    }
  }
}

// ---- persistent scan --------------------------------------------------------
struct SCtx {
  const bf16u *Wp1, *Wp2, *Wpmu, *Wpsig, *Wz1, *Wz2;  // phi weights (global, L2-resident)
  const bf16u *k1, *rk1, *k2, *rk2;                   // packed; slices preloaded to LDS
  const float *bp1, *bp2, *bpmu, *bpsig, *bz1, *bz2, *b1, *b2, *eps;
  const bf16u *X2t;                                   // [t*64+b][256]
  bf16u *zp_all, *S_all, *h1b, *h4b;
  float *out_z;
};

// grid = 68 WGs x 256 threads:
//   wg 0..3   : phi chain, 16 batch rows each (weights streamed from L2)
//   wg 4..35  : GRU1, hidden-unit slice of 16 (rk1+k1 slices LDS-resident, 96KB)
//   wg 36..67 : GRU2, hidden-unit slice of 16 (rk2+k2 slices LDS-resident)
// 3 grid syncs per step: [phi || mh1 || mh4] -> [mx1+GRU1] -> [mx2+GRU2]
__global__ __launch_bounds__(256, 1)
void scan_persist(SCtx c){
  __shared__ __align__(16) char SLDS[98304];
  cg::grid_group grid = cg::this_grid();
  const int lane = threadIdx.x & 63, wave = threadIdx.x >> 6;
  const int wg = blockIdx.x;

  if (wg < 4){
    // ---------------- phi role ----------------
    char* A0  = SLDS;            // 16KB: h4 tile, swizzled [16][1024B]
    char* A1s = SLDS + 16384;    // 8KB
    char* A2s = SLDS + 24576;    // 8KB
    char* A3s = SLDS + 32768;    // 2KB
    const int b0 = wg * 16;
    for (int t = 0; t < 256; ++t){
      const bf16u* X2row = c.X2t + (size_t)t * 64 * 256;
      // stage h4 (bf16) into swizzled LDS
      for (int i = threadIdx.x; i < 1024; i += 256){
        int r = i >> 6, ch = i & 63;
        *(short8*)(A0 + r * 1024 + ((ch * 16) ^ ((r & 7) << 4))) =
            *(const short8*)(c.h4b + (size_t)(b0 + r) * 512 + ch * 8);
      }
      __syncthreads();
      // phi1 = relu(x2@Wp1[:256] + h4@Wp1[256:] + bp1)
      for (int nt = wave; nt < 16; nt += 4){
        f32x4 acc = {0.f,0.f,0.f,0.f};
#pragma unroll
        for (int kc = 0; kc < 8; ++kc)
          acc = MFMA(afrag_g(X2row, 256, b0, kc, lane), wfrag(c.Wp1, 768, nt, kc, lane), acc);
#pragma unroll
        for (int kc = 0; kc < 16; ++kc)
          acc = MFMA(afrag_l(A0, 1024, kc, lane), wfrag(c.Wp1, 768, nt, 8 + kc, lane), acc);
#pragma unroll
        for (int r = 0; r < 4; ++r){
          int row = ((lane >> 4) << 2) + r, col = nt * 16 + (lane & 15);
          lds_store_bf(A1s, 512, row, col, f2bf(fmaxf(acc[r] + c.bp1[col], 0.f)));
        }
      }
      __syncthreads();
      // phi2
      for (int nt = wave; nt < 16; nt += 4){
        f32x4 acc = {0.f,0.f,0.f,0.f};
#pragma unroll
        for (int kc = 0; kc < 8; ++kc)
          acc = MFMA(afrag_l(A1s, 512, kc, lane), wfrag(c.Wp2, 256, nt, kc, lane), acc);
#pragma unroll
        for (int r = 0; r < 4; ++r){
          int row = ((lane >> 4) << 2) + r, col = nt * 16 + (lane & 15);
          lds_store_bf(A2s, 512, row, col, f2bf(fmaxf(acc[r] + c.bp2[col], 0.f)));
        }
      }
      __syncthreads();
      // heads -> z
      {
        int nt = wave;
        f32x4 am = {0.f,0.f,0.f,0.f}, as = {0.f,0.f,0.f,0.f};
#pragma unroll
        for (int kc = 0; kc < 8; ++kc){
          short8 a = afrag_l(A2s, 512, kc, lane);
          am = MFMA(a, wfrag(c.Wpmu, 256, nt, kc, lane), am);
          as = MFMA(a, wfrag(c.Wpsig, 256, nt, kc, lane), as);
        }
#pragma unroll
        for (int r = 0; r < 4; ++r){
          int row = ((lane >> 4) << 2) + r, col = nt * 16 + (lane & 15);
          float mu = am[r] + c.bpmu[col];
          float sg = softplusf_(as[r] + c.bpsig[col]);
          int b = b0 + row;
          float e = c.eps[((size_t)b * 256 + t) * 64 + col];
          float z = mu + sg * e;
          c.out_z[((size_t)b * 256 + t) * 64 + col] = z;
          lds_store_bf(A3s, 128, row, col, f2bf(z));
        }
      }
      __syncthreads();
      // zp1
      for (int nt = wave; nt < 16; nt += 4){
        f32x4 acc = {0.f,0.f,0.f,0.f};
#pragma unroll
        for (int kc = 0; kc < 2; ++kc)
          acc = MFMA(afrag_l(A3s, 128, kc, lane), wfrag(c.Wz1, 64, nt, kc, lane), acc);
#pragma unroll
        for (int r = 0; r < 4; ++r){
          int row = ((lane >> 4) << 2) + r, col = nt * 16 + (lane & 15);
          lds_store_bf(A1s, 512, row, col, f2bf(fmaxf(acc[r] + c.bz1[col], 0.f)));
        }
      }
      __syncthreads();
      // zp2 -> zp_all[t]
      for (int nt = wave; nt < 16; nt += 4){
        f32x4 acc = {0.f,0.f,0.f,0.f};
#pragma unroll
        for (int kc = 0; kc < 8; ++kc)
          acc = MFMA(afrag_l(A1s, 512, kc, lane), wfrag(c.Wz2, 256, nt, kc, lane), acc);
#pragma unroll
        for (int r = 0; r < 4; ++r){
          int row = ((lane >> 4) << 2) + r, col = nt * 16 + (lane & 15);
          c.zp_all[(size_t)(t * 64 + b0 + row) * 256 + col] = f2bf(fmaxf(acc[r] + c.bz2[col], 0.f));
        }
      }
      __syncthreads();   // zp stores drained before the fence in grid.sync
      grid.sync();       // sync1: zp ready
      grid.sync();       // sync2 (idle)
      grid.sync();       // sync3: h4 ready for next step
    }
  } else {
    // ---------------- GRU roles ----------------
    const bool g1 = (wg < 36);
    const int  ui = g1 ? (wg - 4) : (wg - 36);      // 0..31 unit-slice (16 units)
    const int  u0 = ui * 16;
    const bf16u* rkp = g1 ? c.rk1 : c.rk2;
    const bf16u* kkp = g1 ? c.k1  : c.k2;
    const float* bias = g1 ? c.b1 : c.b2;           // [2*1536]
    char* RK = SLDS;                                 // 48KB: rk slice (3 nt-blocks)
    char* KK = SLDS + 49152;                         // 48KB: k  slice
    // preload weight slices to LDS (once, reused 256 steps)
#pragma unroll
    for (int m = 0; m < 2; ++m){
      const bf16u* src = m ? kkp : rkp;
      char* dst = m ? KK : RK;
      for (int g = 0; g < 3; ++g){
        const char* s = (const char*)src + (size_t)(g * 32 + ui) * 16384;
        for (int i = threadIdx.x; i < 1024; i += 256)
          *(float4*)(dst + g * 16384 + i * 16) = *(const float4*)(s + i * 16);
      }
    }
    __syncthreads();

    const int m0 = wave * 16;       // wave owns rows m0..m0+15
    f32x4 hreg = {0.f, 0.f, 0.f, 0.f};   // persistent h slice, fp32
    const f32x4 Z4 = {0.f, 0.f, 0.f, 0.f};

    for (int t = 0; t < 256; ++t){
      // ---- P1: mh = h_prev @ rk (bias folded at combine) ----
      f32x4 mz = Z4, mr = Z4, mh = Z4;
      {
        const bf16u* hsrc = g1 ? c.h1b : c.h4b;
#pragma unroll
        for (int kc = 0; kc < 16; ++kc){
          short8 a = afrag_g(hsrc, 512, m0, kc, lane);
          mz = MFMA(a, lfrag(RK, 0, kc, lane), mz);
          mr = MFMA(a, lfrag(RK, 1, kc, lane), mr);
          mh = MFMA(a, lfrag(RK, 2, kc, lane), mh);
        }
      }
      grid.sync();   // sync1: zp ready
      if (g1){
        // ---- P2: mx1 = [x2|zp] @ k1 ; GRU1 combine -> h1 ----
        f32x4 xz = Z4, xr = Z4, xh = Z4;
        const bf16u* X2row = c.X2t    + (size_t)t * 64 * 256;
        const bf16u* zprow = c.zp_all + (size_t)t * 64 * 256;
#pragma unroll
        for (int kc = 0; kc < 8; ++kc){
          short8 a = afrag_g(X2row, 256, m0, kc, lane);
          xz = MFMA(a, lfrag(KK, 0, kc, lane), xz);
          xr = MFMA(a, lfrag(KK, 1, kc, lane), xr);
          xh = MFMA(a, lfrag(KK, 2, kc, lane), xh);
        }
#pragma unroll
        for (int kc = 0; kc < 8; ++kc){
          short8 a = afrag_g(zprow, 256, m0, kc, lane);
          xz = MFMA(a, lfrag(KK, 0, 8 + kc, lane), xz);
          xr = MFMA(a, lfrag(KK, 1, 8 + kc, lane), xr);
          xh = MFMA(a, lfrag(KK, 2, 8 + kc, lane), xh);
        }
#pragma unroll
        for (int r = 0; r < 4; ++r){
          int row  = m0 + ((lane >> 4) << 2) + r;
          int unit = u0 + (lane & 15);
          float xz_ = xz[r] + bias[unit];
          float xr_ = xr[r] + bias[512 + unit];
          float xh_ = xh[r] + bias[1024 + unit];
          float hz_ = mz[r] + bias[1536 + unit];
          float hr_ = mr[r] + bias[1536 + 512 + unit];
          float hh_ = mh[r] + bias[1536 + 1024 + unit];
          float zg = sigmoidf_(xz_ + hz_);
          float rg = sigmoidf_(xr_ + hr_);
          float hc = tanhf(xh_ + rg * hh_);
          float hn = zg * hreg[r] + (1.f - zg) * hc;
          hreg[r] = hn;
          c.h1b[(size_t)row * 512 + unit] = f2bf(hn);
        }
        __syncthreads();
        grid.sync();   // sync2: s1 ready
        grid.sync();   // sync3
      } else {
        grid.sync();   // sync2: s1 ready
        // ---- P3: mx2 = s1 @ k2 ; GRU2 combine -> h4, S_all ----
        f32x4 xz = Z4, xr = Z4, xh = Z4;
#pragma unroll
        for (int kc = 0; kc < 16; ++kc){
          short8 a = afrag_g(c.h1b, 512, m0, kc, lane);
          xz = MFMA(a, lfrag(KK, 0, kc, lane), xz);
          xr = MFMA(a, lfrag(KK, 1, kc, lane), xr);
          xh = MFMA(a, lfrag(KK, 2, kc, lane), xh);
        }
#pragma unroll
        for (int r = 0; r < 4; ++r){
          int row  = m0 + ((lane >> 4) << 2) + r;
          int unit = u0 + (lane & 15);
          float xz_ = xz[r] + bias[unit];
          float xr_ = xr[r] + bias[512 + unit];
          float xh_ = xh[r] + bias[1024 + unit];
          float hz_ = mz[r] + bias[1536 + unit];
          float hr_ = mr[r] + bias[1536 + 512 + unit];
          float hh_ = mh[r] + bias[1536 + 1024 + unit];
          float zg = sigmoidf_(xz_ + hz_);
          float rg = sigmoidf_(xr_ + hr_);
          float hc = tanhf(xh_ + rg * hh_);
          float hn = zg * hreg[r] + (1.f - zg) * hc;
          hreg[r] = hn;
          bf16u hb = f2bf(hn);
          c.h4b[(size_t)row * 512 + unit] = hb;
          c.S_all[(size_t)(t * 64 + row) * 512 + unit] = hb;
        }
        __syncthreads();
        grid.sync();   // sync3: h4 ready
      }
    }
  }
}

// ---- host ------------------------------------------------------------------
extern "C" void kernel_launch(void* const* d_in, const int* in_sizes, int n_in,
                              void* d_out, int out_size, void* d_ws, size_t ws_size,
                              hipStream_t stream){
  const float* inp   = (const float*)d_in[0];
  const float* eps   = (const float*)d_in[1];
  const float* Wx1   = (const float*)d_in[2];  const float* bx1 = (const float*)d_in[3];
  const float* Wx2   = (const float*)d_in[4];  const float* bx2 = (const float*)d_in[5];
  const float* Wz1   = (const float*)d_in[6];  const float* bz1 = (const float*)d_in[7];
  const float* Wz2   = (const float*)d_in[8];  const float* bz2 = (const float*)d_in[9];
  const float* Wp1   = (const float*)d_in[10]; const float* bp1 = (const float*)d_in[11];
  const float* Wp2   = (const float*)d_in[12]; const float* bp2 = (const float*)d_in[13];
  const float* Wpmu  = (const float*)d_in[14]; const float* bpmu = (const float*)d_in[15];
  const float* Wpsig = (const float*)d_in[16]; const float* bpsig = (const float*)d_in[17];
  // d_in[18..25]: prior path -> DEAD (not in outputs)
  const float* Wt1   = (const float*)d_in[26]; const float* bt1 = (const float*)d_in[27];
  const float* Wt2   = (const float*)d_in[28]; const float* bt2 = (const float*)d_in[29];
  const float* Wtmu  = (const float*)d_in[30]; const float* btmu = (const float*)d_in[31];
  const float* Wtsig = (const float*)d_in[32]; const float* btsig = (const float*)d_in[33];
  const float* k1    = (const float*)d_in[34];
  const float* rk1   = (const float*)d_in[35];
  const float* b1    = (const float*)d_in[36];
  const float* k2    = (const float*)d_in[37];
  const float* rk2   = (const float*)d_in[38];
  const float* b2    = (const float*)d_in[39];

  float* out_mu  = (float*)d_out;
  float* out_sig = out_mu + (size_t)16384 * 128;
  float* out_z   = out_sig + (size_t)16384 * 128;

  char* p = (char*)d_ws;
  auto alloc = [&](size_t bytes)->char*{ char* r = p; p += (bytes + 255) & ~(size_t)255; return r; };

  // packed weights
  bf16u* Wx1p  = (bf16u*)alloc((size_t)128 * 256 * 2);
  bf16u* Wx2p  = (bf16u*)alloc((size_t)256 * 256 * 2);
  bf16u* Wp1p  = (bf16u*)alloc((size_t)768 * 256 * 2);
  bf16u* Wp2p  = (bf16u*)alloc((size_t)256 * 256 * 2);
  bf16u* Wpmup = (bf16u*)alloc((size_t)256 * 64 * 2);
  bf16u* Wpsigp= (bf16u*)alloc((size_t)256 * 64 * 2);
  bf16u* Wz1p  = (bf16u*)alloc((size_t)64 * 256 * 2);
  bf16u* Wz2p  = (bf16u*)alloc((size_t)256 * 256 * 2);
  bf16u* Wt1p  = (bf16u*)alloc((size_t)768 * 256 * 2);
  bf16u* Wt2p  = (bf16u*)alloc((size_t)256 * 256 * 2);
  bf16u* Wtmup = (bf16u*)alloc((size_t)256 * 128 * 2);
  bf16u* Wtsigp= (bf16u*)alloc((size_t)256 * 128 * 2);
  bf16u* k1p   = (bf16u*)alloc((size_t)512 * 1536 * 2);
  bf16u* rk1p  = (bf16u*)alloc((size_t)512 * 1536 * 2);
  bf16u* k2p   = (bf16u*)alloc((size_t)512 * 1536 * 2);
  bf16u* rk2p  = (bf16u*)alloc((size_t)512 * 1536 * 2);

  // activations
  bf16u* Xbf    = (bf16u*)alloc((size_t)16384 * 128 * 2);
  bf16u* tmp1   = (bf16u*)alloc((size_t)16384 * 256 * 2);   // reused as th1
  bf16u* X2t    = (bf16u*)alloc((size_t)16384 * 256 * 2);   // reused as th2
  bf16u* zp_all = (bf16u*)alloc((size_t)16384 * 256 * 2);
  bf16u* S_all  = (bf16u*)alloc((size_t)16384 * 512 * 2);
  bf16u* h1b    = (bf16u*)alloc((size_t)64 * 512 * 2);
  bf16u* h4b    = (bf16u*)alloc((size_t)64 * 512 * 2);
  bf16u* th1 = tmp1;
  bf16u* th2 = X2t;

  auto PK = [&](const float* src, bf16u* dst, int K, int N){
    pack_w<<<dim3((N / 16) * (K / 32)), dim3(64), 0, stream>>>(src, dst, K, N);
  };
  PK(Wx1, Wx1p, 128, 256);
  PK(Wx2, Wx2p, 256, 256);
  PK(Wp1, Wp1p, 768, 256);
  PK(Wp2, Wp2p, 256, 256);
  PK(Wpmu, Wpmup, 256, 64);
  PK(Wpsig, Wpsigp, 256, 64);
  PK(Wz1, Wz1p, 64, 256);
  PK(Wz2, Wz2p, 256, 256);
  PK(Wt1, Wt1p, 768, 256);
  PK(Wt2, Wt2p, 256, 256);
  PK(Wtmu, Wtmup, 256, 128);
  PK(Wtsig, Wtsigp, 256, 128);
  PK(k1, k1p, 512, 1536);
  PK(rk1, rk1p, 512, 1536);
  PK(k2, k2p, 512, 1536);
  PK(rk2, rk2p, 512, 1536);

  cvt_bf<<<dim3((16384 * 128 + 255) / 256), dim3(256), 0, stream>>>(inp, Xbf, 16384 * 128);
  hipMemsetAsync(h1b, 0, (size_t)64 * 512 * 2, stream);
  hipMemsetAsync(h4b, 0, (size_t)64 * 512 * 2, stream);

  // X transform; second layer stores time-major [t*64+b][256]
  gemm_big<1, 0><<<dim3(256, 4), dim3(256), 0, stream>>>(Xbf, 128, nullptr, 0, Wx1p, bx1, tmp1, 256);
  gemm_big<1, 1><<<dim3(256, 4), dim3(256), 0, stream>>>(tmp1, 256, nullptr, 0, Wx2p, bx2, X2t, 256);

  SCtx sc;
  sc.Wp1 = Wp1p; sc.Wp2 = Wp2p; sc.Wpmu = Wpmup; sc.Wpsig = Wpsigp;
  sc.Wz1 = Wz1p; sc.Wz2 = Wz2p;
  sc.k1 = k1p; sc.rk1 = rk1p; sc.k2 = k2p; sc.rk2 = rk2p;
  sc.bp1 = bp1; sc.bp2 = bp2; sc.bpmu = bpmu; sc.bpsig = bpsig;
  sc.bz1 = bz1; sc.bz2 = bz2; sc.b1 = b1; sc.b2 = b2; sc.eps = eps;
  sc.X2t = X2t; sc.zp_all = zp_all; sc.S_all = S_all;
  sc.h1b = h1b; sc.h4b = h4b; sc.out_z = out_z;

  void* args[] = { (void*)&sc };
  hipLaunchCooperativeKernel((const void*)scan_persist, dim3(68), dim3(256), args, 0, stream);

  // theta decoder
  gemm_big<1, 0><<<dim3(256, 4), dim3(256), 0, stream>>>(zp_all, 256, S_all, 512, Wt1p, bt1, th1, 256);
  gemm_big<1, 0><<<dim3(256, 4), dim3(256), 0, stream>>>(th1, 256, nullptr, 0, Wt2p, bt2, th2, 256);
  gemm_heads<<<dim3(256, 2), dim3(256), 0, stream>>>(th2, Wtmup, Wtsigp, btmu, btsig, out_mu, out_sig);
}